// Round 17
// baseline (246.258 us; speedup 1.0000x reference)
//
#include <hip/hip_runtime.h>
#include <hip/hip_bf16.h>

#define DIM 256
#define MEMN 512
#define TEMPF 10.0f

typedef float f32x4 __attribute__((ext_vector_type(4)));
typedef __bf16 bf16x8 __attribute__((ext_vector_type(8)));
typedef unsigned int u32;
typedef unsigned short u16;
typedef u32 u32x4 __attribute__((ext_vector_type(4)));

__device__ __forceinline__ u16 bf16bits(float x) {
  __bf16 h = (__bf16)x;
  return __builtin_bit_cast(u16, h);
}
__device__ __forceinline__ u32 pack2(float a, float b) {
  return (u32)bf16bits(a) | ((u32)bf16bits(b) << 16);
}
// NT fragment load: bypass/no-allocate L1/L2 -> frags never compete with the
// write stream for L2; they stream from L3 (512 KB, permanently resident).
__device__ __forceinline__ bf16x8 nt_frag(const u16* p) {
  u32x4 v = __builtin_nontemporal_load(reinterpret_cast<const u32x4*>(p));
  return __builtin_bit_cast(bf16x8, v);
}

// KnFrag[kc][mt][lane][j] = Kn_norm[mt*16+(lane&15)][kc*32+(lane>>4)*8+j], kc<8, mt<32
__global__ void prep_keys(const float* __restrict__ keys, u16* __restrict__ knf) {
  int lane = threadIdx.x & 63;
  int m = blockIdx.x * 4 + (threadIdx.x >> 6);
  float4 v = *reinterpret_cast<const float4*>(keys + (size_t)m * DIM + lane * 4);
  float ss = v.x*v.x + v.y*v.y + v.z*v.z + v.w*v.w;
  #pragma unroll
  for (int o = 1; o < 64; o <<= 1) ss += __shfl_xor(ss, o);
  float rn = 1.0f / fmaxf(sqrtf(ss), 1e-12f);
  float vals[4] = {v.x*rn, v.y*rn, v.z*rn, v.w*rn};
  int mt = m >> 4, ml = m & 15;
  #pragma unroll
  for (int t = 0; t < 4; ++t) {
    int d = lane * 4 + t;
    int kc = d >> 5, gg = (d >> 3) & 3, j = d & 7;
    knf[(size_t)((kc*32 + mt)*64 + gg*16 + ml)*8 + j] = bf16bits(vals[t]);
  }
}

// VtFrag[kc][dt][lane][j] = V[kc*32+(lane>>4)*8+j][dt*16+(lane&15)], kc<16, dt<16
__global__ void prep_vals(const float* __restrict__ mv, u16* __restrict__ vtf) {
  int lane = threadIdx.x & 63;
  int m = blockIdx.x * 4 + (threadIdx.x >> 6);
  float4 v = *reinterpret_cast<const float4*>(mv + (size_t)m * DIM + lane * 4);
  float vals[4] = {v.x, v.y, v.z, v.w};
  int kc = m >> 5, gg = (m >> 3) & 3, j = m & 7;
  #pragma unroll
  for (int t = 0; t < 4; ++t) {
    int d = lane * 4 + t;
    int dt = d >> 4, dl = d & 15;
    vtf[(size_t)((kc*16 + dt)*64 + gg*16 + dl)*8 + j] = bf16bits(vals[t]);
  }
}

// lgkm-only barrier: drains this wave's LDS queue, syncs waves, never touches
// vmcnt -> global stores drain in the background (round-12/14-validated).
#define BAR_LGKM do { \
    asm volatile("s_waitcnt lgkmcnt(0)" ::: "memory"); \
    __builtin_amdgcn_s_barrier(); \
  } while (0)

// Round-14 structure verbatim; cache-role inversion:
//   frag reads (K,V) -> NT loads (no L2 allocate; stream from L3)
//   W/O stores -> CACHED (L2 = pure write-combining buffer, fill-kernel mode)
//   Q loads stay NT. Mid-kernel W epilogue + lgkm-only barriers unchanged.
__global__ __launch_bounds__(256, 2) void fused_main(
    const float* __restrict__ q, const u16* __restrict__ knf,
    const u16* __restrict__ vtf, float* __restrict__ out_o,
    float* __restrict__ out_w, float* __restrict__ out_s) {
  // [0,32768): frag region: Q-frags (gr*8+kc)*1024+lane*16; then wave-private
  //            8KB epilogue quarters; then W-frag halves.
  // [32768,33792): psb row-sum partials; [33792,34048): rnb 1/||q||
  __shared__ __align__(16) char lds[34048];
  const int tid = threadIdx.x;
  const int wave = tid >> 6, lane = tid & 63;
  const int g = lane >> 4, c = lane & 15;
  const int browbase = blockIdx.x * 64;
  const int myrow = browbase + wave * 16 + c;

  float* psb = reinterpret_cast<float*>(lds + 32768);
  float* rnb = reinterpret_cast<float*>(lds + 33792);

  // ---- prologue: own 16 rows' Q (NT loads) -> scene, sum-sq, bf16 frags
  const float* qrow = q + (size_t)myrow * DIM + g * 8;
  float sd = 0.f, ss = 0.f;
  #pragma unroll
  for (int kc = 0; kc < 8; ++kc) {
    f32x4 a = __builtin_nontemporal_load(reinterpret_cast<const f32x4*>(qrow + kc*32));
    f32x4 b = __builtin_nontemporal_load(reinterpret_cast<const f32x4*>(qrow + kc*32 + 4));
    float x[8] = {a[0], a[1], a[2], a[3], b[0], b[1], b[2], b[3]};
    bf16x8 qb;
    #pragma unroll
    for (int e = 0; e < 8; ++e) {
      float nb = __shfl_down(x[e], 1);       // row c+1 (valid c<15)
      float d0 = nb - x[e];
      sd += d0 * d0;
      ss += x[e] * x[e];
      qb[e] = (__bf16)x[e];                  // deferred norm -> exp scale
    }
    *reinterpret_cast<bf16x8*>(lds + (wave*8 + kc)*1024 + lane*16) = qb;
  }
  sd += __shfl_xor(sd, 16); sd += __shfl_xor(sd, 32);
  ss += __shfl_xor(ss, 16); ss += __shfl_xor(ss, 32);
  if (g == 0 && c < 15)
    out_s[myrow] = (sqrtf(sd) < 0.8f) ? 1.0f : 0.0f;
  float rn = 1.0f / fmaxf(sqrtf(ss), 1e-12f);
  if (g == 0) rnb[wave*16 + c] = rn;
  BAR_LGKM;                                  // #1: Q-frags + rn visible

  float scale_r[4];
  #pragma unroll
  for (int gr = 0; gr < 4; ++gr) scale_r[gr] = TEMPF * rnb[gr*16 + c];

  // ---- GEMM1: S^T[m in wave-quarter][64 rows]; A (K) via NT from L3
  f32x4 acc[8][4];
  #pragma unroll
  for (int mt = 0; mt < 8; ++mt)
    #pragma unroll
    for (int gr = 0; gr < 4; ++gr) { f32x4 z = {}; acc[mt][gr] = z; }

  #pragma unroll
  for (int kc = 0; kc < 8; ++kc) {
    bf16x8 bfr[4];
    #pragma unroll
    for (int gr = 0; gr < 4; ++gr)
      bfr[gr] = *reinterpret_cast<const bf16x8*>(lds + (gr*8 + kc)*1024 + lane*16);
    bf16x8 afr[8];
    #pragma unroll
    for (int mt = 0; mt < 8; ++mt)
      afr[mt] = nt_frag(knf + (size_t)(kc*32 + wave*8 + mt)*512 + lane*8);
    #pragma unroll
    for (int mt = 0; mt < 8; ++mt)
      #pragma unroll
      for (int gr = 0; gr < 4; ++gr)
        acc[mt][gr] = __builtin_amdgcn_mfma_f32_16x16x32_bf16(afr[mt], bfr[gr], acc[mt][gr], 0, 0, 0);
  }
  // acc[mt][gr][i] = S^T[m=128w+16mt+4g+i][row=gr*16+c]

  // ---- exp + partial row sums
  float psum[4] = {0.f, 0.f, 0.f, 0.f};
  #pragma unroll
  for (int mt = 0; mt < 8; ++mt)
    #pragma unroll
    for (int gr = 0; gr < 4; ++gr)
      #pragma unroll
      for (int i = 0; i < 4; ++i) {
        float e = __expf(acc[mt][gr][i] * scale_r[gr]);
        acc[mt][gr][i] = e;
        psum[gr] += e;
      }
  #pragma unroll
  for (int gr = 0; gr < 4; ++gr) {
    psum[gr] += __shfl_xor(psum[gr], 16);
    psum[gr] += __shfl_xor(psum[gr], 32);
  }
  if (g == 0) {
    #pragma unroll
    for (int gr = 0; gr < 4; ++gr)
      psb[(wave*4 + gr)*16 + c] = psum[gr];
  }
  BAR_LGKM;                                  // #2: partials visible; Q-frags dead

  float rcp_r[4];
  #pragma unroll
  for (int gr = 0; gr < 4; ++gr) {
    float t = psb[(0*4 + gr)*16 + c] + psb[(1*4 + gr)*16 + c]
            + psb[(2*4 + gr)*16 + c] + psb[(3*4 + gr)*16 + c];
    rcp_r[gr] = 1.0f / t;
  }
  // fold rcp: acc becomes final W (f32)
  #pragma unroll
  for (int mt = 0; mt < 8; ++mt)
    #pragma unroll
    for (int gr = 0; gr < 4; ++gr)
      #pragma unroll
      for (int i = 0; i < 4; ++i)
        acc[mt][gr][i] *= rcp_r[gr];

  // ---- W epilogue NOW (wave-private 8KB quarter of frag region):
  // acc[mt][gr][i] = W[row=gr*16+c][m=128w+mt*16+4g+i]; 4 passes of 16 rows;
  // full-line (512B) CACHED stores -> L2 write-combining; drain under GEMM2.
  char* priv = lds + wave * 8192;
  #pragma unroll
  for (int gw = 0; gw < 4; ++gw) {
    #pragma unroll
    for (int mt = 0; mt < 8; ++mt)
      *reinterpret_cast<f32x4*>(priv + c*512 + ((mt*64 + g*16) ^ (c << 4))) = acc[mt][gw];
    asm volatile("s_waitcnt lgkmcnt(0)" ::: "memory");   // wave-private: no barrier
    #pragma unroll
    for (int p = 0; p < 8; ++p) {
      int rq = lane >> 5, cc = lane & 31;
      int rowp = 2*p + rq;
      f32x4 t = *reinterpret_cast<const f32x4*>(priv + rowp*512 + ((cc*16) ^ ((rowp & 15) << 4)));
      *reinterpret_cast<f32x4*>(
          out_w + (size_t)(browbase + gw*16 + rowp)*MEMN + wave*128 + cc*4) = t;
    }
  }

  // pack acc -> bf16 pairs; acc dies here (register relief for GEMM2)
  u32 hp[8][8];                              // hp[mt][gr*2+s]
  #pragma unroll
  for (int mt = 0; mt < 8; ++mt)
    #pragma unroll
    for (int gr = 0; gr < 4; ++gr) {
      hp[mt][gr*2+0] = pack2(acc[mt][gr][0], acc[mt][gr][1]);
      hp[mt][gr*2+1] = pack2(acc[mt][gr][2], acc[mt][gr][3]);
    }
  BAR_LGKM;                                  // #3: all epilogue LDS reads done

  // W-frag writer (round-6-verified mapping, from hp):
  // kcw=4w+(mt>>1), lane_t=((mt&1)*2+(g>>1))*16+c, dword j0=(g&1)
#define WFRAG_WRITE(SLOTBASE) \
    _Pragma("unroll") \
    for (int mt = 0; mt < 8; ++mt) { \
      int slot = (4*wave + (mt >> 1) - (SLOTBASE)) * 4; \
      int lane_t = ((mt & 1)*2 + (g >> 1))*16 + c; \
      _Pragma("unroll") \
      for (int gr = 0; gr < 4; ++gr) { \
        u32* dst = reinterpret_cast<u32*>(lds + (size_t)(slot + gr)*1024 + lane_t*16 + (g & 1)*8); \
        dst[0] = hp[mt][gr*2+0]; dst[1] = hp[mt][gr*2+1]; \
      } \
    }

  f32x4 oacc[4][4];
  #pragma unroll
  for (int dt = 0; dt < 4; ++dt)
    #pragma unroll
    for (int gr = 0; gr < 4; ++gr) { f32x4 z = {}; oacc[dt][gr] = z; }

  // ---- W-frag half A (kcw 0..7: waves 0,1)
  if (wave < 2) { WFRAG_WRITE(0) }
  BAR_LGKM;                                  // #4: half A visible

  // ---- GEMM2 pass A: kc2 0..7; A (V) via NT from L3
  #pragma unroll
  for (int kc2 = 0; kc2 < 8; ++kc2) {
    bf16x8 bfr[4];
    #pragma unroll
    for (int gr = 0; gr < 4; ++gr)
      bfr[gr] = *reinterpret_cast<const bf16x8*>(lds + (size_t)(kc2*4 + gr)*1024 + lane*16);
    bf16x8 afr[4];
    #pragma unroll
    for (int dt = 0; dt < 4; ++dt)
      afr[dt] = nt_frag(vtf + (size_t)(kc2*16 + wave*4 + dt)*512 + lane*8);
    #pragma unroll
    for (int dt = 0; dt < 4; ++dt)
      #pragma unroll
      for (int gr = 0; gr < 4; ++gr)
        oacc[dt][gr] = __builtin_amdgcn_mfma_f32_16x16x32_bf16(afr[dt], bfr[gr], oacc[dt][gr], 0, 0, 0);
  }
  BAR_LGKM;                                  // #5: half A consumed

  // ---- W-frag half B (kcw 8..15: waves 2,3)
  if (wave >= 2) { WFRAG_WRITE(8) }
  BAR_LGKM;                                  // #6: half B visible

  // ---- GEMM2 pass B: kc2 8..15
  #pragma unroll
  for (int kc2 = 8; kc2 < 16; ++kc2) {
    bf16x8 bfr[4];
    #pragma unroll
    for (int gr = 0; gr < 4; ++gr)
      bfr[gr] = *reinterpret_cast<const bf16x8*>(lds + (size_t)((kc2-8)*4 + gr)*1024 + lane*16);
    bf16x8 afr[4];
    #pragma unroll
    for (int dt = 0; dt < 4; ++dt)
      afr[dt] = nt_frag(vtf + (size_t)(kc2*16 + wave*4 + dt)*512 + lane*8);
    #pragma unroll
    for (int dt = 0; dt < 4; ++dt)
      #pragma unroll
      for (int gr = 0; gr < 4; ++gr)
        oacc[dt][gr] = __builtin_amdgcn_mfma_f32_16x16x32_bf16(afr[dt], bfr[gr], oacc[dt][gr], 0, 0, 0);
  }
  BAR_LGKM;                                  // #7: frag region dead -> private

  // ---- O epilogue (8KB wave-private; 2 passes of 32 rows; 256B cached stores)
  #pragma unroll
  for (int ho = 0; ho < 2; ++ho) {
    #pragma unroll
    for (int dt = 0; dt < 4; ++dt)
      #pragma unroll
      for (int grl = 0; grl < 2; ++grl) {
        int rowl = grl*16 + c;
        *reinterpret_cast<f32x4*>(priv + rowl*256 + ((dt*64 + g*16) ^ (c << 4))) = oacc[dt][ho*2 + grl];
      }
    asm volatile("s_waitcnt lgkmcnt(0)" ::: "memory");
    #pragma unroll
    for (int p = 0; p < 8; ++p) {
      int rq = lane >> 4, cc = lane & 15;
      int rowp = 4*p + rq;
      f32x4 t = *reinterpret_cast<const f32x4*>(priv + rowp*256 + ((cc*16) ^ ((rowp & 15) << 4)));
      *reinterpret_cast<f32x4*>(
          out_o + (size_t)(browbase + ho*32 + rowp)*DIM + wave*64 + cc*4) = t;
    }
  }
}

// Boundary scene diffs: i % 16 == 15 (one wave per i)
__global__ void scene_bound(const float* __restrict__ q, float* __restrict__ out_s, int B) {
  int widx = (blockIdx.x * blockDim.x + threadIdx.x) >> 6;
  int lane = threadIdx.x & 63;
  int i = widx * 16 + 15;
  if (i > B - 2) return;
  const float* a = q + (size_t)i * DIM + lane * 4;
  float4 x = *reinterpret_cast<const float4*>(a);
  float4 y = *reinterpret_cast<const float4*>(a + DIM);
  float dx = y.x-x.x, dy = y.y-x.y, dz = y.z-x.z, dw = y.w-x.w;
  float sd = dx*dx + dy*dy + dz*dz + dw*dw;
  #pragma unroll
  for (int o = 1; o < 64; o <<= 1) sd += __shfl_xor(sd, o);
  if (lane == 0) out_s[i] = (sqrtf(sd) < 0.8f) ? 1.0f : 0.0f;
}

extern "C" void kernel_launch(void* const* d_in, const int* in_sizes, int n_in,
                              void* d_out, int out_size, void* d_ws, size_t ws_size,
                              hipStream_t stream) {
  const float* q  = (const float*)d_in[0];
  const float* mk = (const float*)d_in[1];
  const float* mv = (const float*)d_in[2];
  int B = in_sizes[0] / DIM;            // 131072
  float* o = (float*)d_out;
  float* w = o + (size_t)B * DIM;
  float* s = w + (size_t)B * MEMN;
  u16* knf = (u16*)d_ws;                         // 256 KB
  u16* vtf = (u16*)((char*)d_ws + 262144);       // 256 KB
  prep_keys<<<128, 256, 0, stream>>>(mk, knf);
  prep_vals<<<128, 256, 0, stream>>>(mv, vtf);
  fused_main<<<B / 64, 256, 0, stream>>>(q, knf, vtf, o, w, s);
  int nwaves = B / 16;
  scene_bound<<<(nwaves + 3) / 4, 256, 0, stream>>>(q, s, B);
}

// Round 18
// 155.798 us; speedup vs baseline: 1.5806x; 1.5806x over previous
//
#include <hip/hip_runtime.h>
#include <hip/hip_bf16.h>

#define DIM 256
#define MEMN 512
#define TEMPF 10.0f

typedef float f32x4 __attribute__((ext_vector_type(4)));
typedef __bf16 bf16x8 __attribute__((ext_vector_type(8)));
typedef unsigned int u32;
typedef unsigned short u16;

__device__ __forceinline__ u16 bf16bits(float x) {
  __bf16 h = (__bf16)x;
  return __builtin_bit_cast(u16, h);
}
__device__ __forceinline__ u32 pack2(float a, float b) {
  return (u32)bf16bits(a) | ((u32)bf16bits(b) << 16);
}

// Combined auxiliary kernel (one launch):
//  blocks [0,128):    prep_keys  -> KnFrag (normalized)
//  blocks [128,256):  prep_vals  -> VtFrag
//  blocks [256,2304): scene boundary diffs for i % 16 == 15
__global__ void aux_kernel(const float* __restrict__ keys,
                           const float* __restrict__ mv,
                           const float* __restrict__ q,
                           u16* __restrict__ knf, u16* __restrict__ vtf,
                           float* __restrict__ out_s, int B) {
  int lane = threadIdx.x & 63;
  int wave = threadIdx.x >> 6;
  if (blockIdx.x < 128) {
    int m = blockIdx.x * 4 + wave;
    float4 v = *reinterpret_cast<const float4*>(keys + (size_t)m * DIM + lane * 4);
    float ss = v.x*v.x + v.y*v.y + v.z*v.z + v.w*v.w;
    #pragma unroll
    for (int o = 1; o < 64; o <<= 1) ss += __shfl_xor(ss, o);
    float rn = 1.0f / fmaxf(sqrtf(ss), 1e-12f);
    float vals[4] = {v.x*rn, v.y*rn, v.z*rn, v.w*rn};
    int mt = m >> 4, ml = m & 15;
    #pragma unroll
    for (int t = 0; t < 4; ++t) {
      int d = lane * 4 + t;
      int kc = d >> 5, gg = (d >> 3) & 3, j = d & 7;
      knf[(size_t)((kc*32 + mt)*64 + gg*16 + ml)*8 + j] = bf16bits(vals[t]);
    }
  } else if (blockIdx.x < 256) {
    int m = (blockIdx.x - 128) * 4 + wave;
    float4 v = *reinterpret_cast<const float4*>(mv + (size_t)m * DIM + lane * 4);
    float vals[4] = {v.x, v.y, v.z, v.w};
    int kc = m >> 5, gg = (m >> 3) & 3, j = m & 7;
    #pragma unroll
    for (int t = 0; t < 4; ++t) {
      int d = lane * 4 + t;
      int dt = d >> 4, dl = d & 15;
      vtf[(size_t)((kc*16 + dt)*64 + gg*16 + dl)*8 + j] = bf16bits(vals[t]);
    }
  } else {
    int widx = (blockIdx.x - 256) * 4 + wave;
    int i = widx * 16 + 15;
    if (i > B - 2) return;
    const float* a = q + (size_t)i * DIM + lane * 4;
    float4 x = *reinterpret_cast<const float4*>(a);
    float4 y = *reinterpret_cast<const float4*>(a + DIM);
    float dx = y.x-x.x, dy = y.y-x.y, dz = y.z-x.z, dw = y.w-x.w;
    float sd = dx*dx + dy*dy + dz*dz + dw*dw;
    #pragma unroll
    for (int o = 1; o < 64; o <<= 1) sd += __shfl_xor(sd, o);
    if (lane == 0) out_s[i] = (sqrtf(sd) < 0.8f) ? 1.0f : 0.0f;
  }
}

// lgkm-only barrier: drains this wave's LDS queue, syncs waves, never touches
// vmcnt -> global stores drain in the background (round-12/14-validated).
#define BAR_LGKM do { \
    asm volatile("s_waitcnt lgkmcnt(0)" ::: "memory"); \
    __builtin_amdgcn_s_barrier(); \
  } while (0)

// Round-14 structure; hybrid store paths: W = NT (mid-kernel, drains under
// GEMM2 — R14-proven), O = cached (tail; L2 write-combining absorbs 64KB/block
// and the block retires without waiting on the slow NT path).
__global__ __launch_bounds__(256, 2) void fused_main(
    const float* __restrict__ q, const u16* __restrict__ knf,
    const u16* __restrict__ vtf, float* __restrict__ out_o,
    float* __restrict__ out_w, float* __restrict__ out_s) {
  // [0,32768): frag region: Q-frags (gr*8+kc)*1024+lane*16; then wave-private
  //            8KB epilogue quarters; then W-frag halves.
  // [32768,33792): psb row-sum partials; [33792,34048): rnb 1/||q||
  __shared__ __align__(16) char lds[34048];
  const int tid = threadIdx.x;
  const int wave = tid >> 6, lane = tid & 63;
  const int g = lane >> 4, c = lane & 15;
  const int browbase = blockIdx.x * 64;
  const int myrow = browbase + wave * 16 + c;

  float* psb = reinterpret_cast<float*>(lds + 32768);
  float* rnb = reinterpret_cast<float*>(lds + 33792);

  // ---- prologue: own 16 rows' Q (NT loads) -> scene, sum-sq, bf16 frags
  const float* qrow = q + (size_t)myrow * DIM + g * 8;
  float sd = 0.f, ss = 0.f;
  #pragma unroll
  for (int kc = 0; kc < 8; ++kc) {
    f32x4 a = __builtin_nontemporal_load(reinterpret_cast<const f32x4*>(qrow + kc*32));
    f32x4 b = __builtin_nontemporal_load(reinterpret_cast<const f32x4*>(qrow + kc*32 + 4));
    float x[8] = {a[0], a[1], a[2], a[3], b[0], b[1], b[2], b[3]};
    bf16x8 qb;
    #pragma unroll
    for (int e = 0; e < 8; ++e) {
      float nb = __shfl_down(x[e], 1);       // row c+1 (valid c<15)
      float d0 = nb - x[e];
      sd += d0 * d0;
      ss += x[e] * x[e];
      qb[e] = (__bf16)x[e];                  // deferred norm -> exp scale
    }
    *reinterpret_cast<bf16x8*>(lds + (wave*8 + kc)*1024 + lane*16) = qb;
  }
  sd += __shfl_xor(sd, 16); sd += __shfl_xor(sd, 32);
  ss += __shfl_xor(ss, 16); ss += __shfl_xor(ss, 32);
  if (g == 0 && c < 15)
    out_s[myrow] = (sqrtf(sd) < 0.8f) ? 1.0f : 0.0f;
  float rn = 1.0f / fmaxf(sqrtf(ss), 1e-12f);
  if (g == 0) rnb[wave*16 + c] = rn;
  BAR_LGKM;                                  // #1: Q-frags + rn visible

  float scale_r[4];
  #pragma unroll
  for (int gr = 0; gr < 4; ++gr) scale_r[gr] = TEMPF * rnb[gr*16 + c];

  // ---- GEMM1: S^T[m in wave-quarter][64 rows]; A (K) direct from L2 (cached)
  f32x4 acc[8][4];
  #pragma unroll
  for (int mt = 0; mt < 8; ++mt)
    #pragma unroll
    for (int gr = 0; gr < 4; ++gr) { f32x4 z = {}; acc[mt][gr] = z; }

  #pragma unroll
  for (int kc = 0; kc < 8; ++kc) {
    bf16x8 bfr[4];
    #pragma unroll
    for (int gr = 0; gr < 4; ++gr)
      bfr[gr] = *reinterpret_cast<const bf16x8*>(lds + (gr*8 + kc)*1024 + lane*16);
    bf16x8 afr[8];
    #pragma unroll
    for (int mt = 0; mt < 8; ++mt)
      afr[mt] = *reinterpret_cast<const bf16x8*>(
          knf + (size_t)(kc*32 + wave*8 + mt)*512 + lane*8);
    #pragma unroll
    for (int mt = 0; mt < 8; ++mt)
      #pragma unroll
      for (int gr = 0; gr < 4; ++gr)
        acc[mt][gr] = __builtin_amdgcn_mfma_f32_16x16x32_bf16(afr[mt], bfr[gr], acc[mt][gr], 0, 0, 0);
  }
  // acc[mt][gr][i] = S^T[m=128w+16mt+4g+i][row=gr*16+c]

  // ---- exp + partial row sums
  float psum[4] = {0.f, 0.f, 0.f, 0.f};
  #pragma unroll
  for (int mt = 0; mt < 8; ++mt)
    #pragma unroll
    for (int gr = 0; gr < 4; ++gr)
      #pragma unroll
      for (int i = 0; i < 4; ++i) {
        float e = __expf(acc[mt][gr][i] * scale_r[gr]);
        acc[mt][gr][i] = e;
        psum[gr] += e;
      }
  #pragma unroll
  for (int gr = 0; gr < 4; ++gr) {
    psum[gr] += __shfl_xor(psum[gr], 16);
    psum[gr] += __shfl_xor(psum[gr], 32);
  }
  if (g == 0) {
    #pragma unroll
    for (int gr = 0; gr < 4; ++gr)
      psb[(wave*4 + gr)*16 + c] = psum[gr];
  }
  BAR_LGKM;                                  // #2: partials visible; Q-frags dead

  float rcp_r[4];
  #pragma unroll
  for (int gr = 0; gr < 4; ++gr) {
    float t = psb[(0*4 + gr)*16 + c] + psb[(1*4 + gr)*16 + c]
            + psb[(2*4 + gr)*16 + c] + psb[(3*4 + gr)*16 + c];
    rcp_r[gr] = 1.0f / t;
  }
  // fold rcp: acc becomes final W (f32)
  #pragma unroll
  for (int mt = 0; mt < 8; ++mt)
    #pragma unroll
    for (int gr = 0; gr < 4; ++gr)
      #pragma unroll
      for (int i = 0; i < 4; ++i)
        acc[mt][gr][i] *= rcp_r[gr];

  // ---- W epilogue NOW (wave-private 8KB quarter of frag region):
  // acc[mt][gr][i] = W[row=gr*16+c][m=128w+mt*16+4g+i]; 4 passes of 16 rows;
  // full-line (512B) NT stores -> drain under GEMM2 + O epilogue.
  char* priv = lds + wave * 8192;
  #pragma unroll
  for (int gw = 0; gw < 4; ++gw) {
    #pragma unroll
    for (int mt = 0; mt < 8; ++mt)
      *reinterpret_cast<f32x4*>(priv + c*512 + ((mt*64 + g*16) ^ (c << 4))) = acc[mt][gw];
    asm volatile("s_waitcnt lgkmcnt(0)" ::: "memory");   // wave-private: no barrier
    #pragma unroll
    for (int p = 0; p < 8; ++p) {
      int rq = lane >> 5, cc = lane & 31;
      int rowp = 2*p + rq;
      f32x4 t = *reinterpret_cast<const f32x4*>(priv + rowp*512 + ((cc*16) ^ ((rowp & 15) << 4)));
      __builtin_nontemporal_store(t, reinterpret_cast<f32x4*>(
          out_w + (size_t)(browbase + gw*16 + rowp)*MEMN + wave*128 + cc*4));
    }
  }

  // pack acc -> bf16 pairs; acc dies here (register relief for GEMM2)
  u32 hp[8][8];                              // hp[mt][gr*2+s]
  #pragma unroll
  for (int mt = 0; mt < 8; ++mt)
    #pragma unroll
    for (int gr = 0; gr < 4; ++gr) {
      hp[mt][gr*2+0] = pack2(acc[mt][gr][0], acc[mt][gr][1]);
      hp[mt][gr*2+1] = pack2(acc[mt][gr][2], acc[mt][gr][3]);
    }
  BAR_LGKM;                                  // #3: all epilogue LDS reads done

  // W-frag writer (round-6-verified mapping, from hp):
  // kcw=4w+(mt>>1), lane_t=((mt&1)*2+(g>>1))*16+c, dword j0=(g&1)
#define WFRAG_WRITE(SLOTBASE) \
    _Pragma("unroll") \
    for (int mt = 0; mt < 8; ++mt) { \
      int slot = (4*wave + (mt >> 1) - (SLOTBASE)) * 4; \
      int lane_t = ((mt & 1)*2 + (g >> 1))*16 + c; \
      _Pragma("unroll") \
      for (int gr = 0; gr < 4; ++gr) { \
        u32* dst = reinterpret_cast<u32*>(lds + (size_t)(slot + gr)*1024 + lane_t*16 + (g & 1)*8); \
        dst[0] = hp[mt][gr*2+0]; dst[1] = hp[mt][gr*2+1]; \
      } \
    }

  f32x4 oacc[4][4];
  #pragma unroll
  for (int dt = 0; dt < 4; ++dt)
    #pragma unroll
    for (int gr = 0; gr < 4; ++gr) { f32x4 z = {}; oacc[dt][gr] = z; }

  // ---- W-frag half A (kcw 0..7: waves 0,1)
  if (wave < 2) { WFRAG_WRITE(0) }
  BAR_LGKM;                                  // #4: half A visible

  // ---- GEMM2 pass A: kc2 0..7; A (V) direct from L2 (cached)
  #pragma unroll
  for (int kc2 = 0; kc2 < 8; ++kc2) {
    bf16x8 bfr[4];
    #pragma unroll
    for (int gr = 0; gr < 4; ++gr)
      bfr[gr] = *reinterpret_cast<const bf16x8*>(lds + (size_t)(kc2*4 + gr)*1024 + lane*16);
    bf16x8 afr[4];
    #pragma unroll
    for (int dt = 0; dt < 4; ++dt)
      afr[dt] = *reinterpret_cast<const bf16x8*>(
          vtf + (size_t)(kc2*16 + wave*4 + dt)*512 + lane*8);
    #pragma unroll
    for (int dt = 0; dt < 4; ++dt)
      #pragma unroll
      for (int gr = 0; gr < 4; ++gr)
        oacc[dt][gr] = __builtin_amdgcn_mfma_f32_16x16x32_bf16(afr[dt], bfr[gr], oacc[dt][gr], 0, 0, 0);
  }
  BAR_LGKM;                                  // #5: half A consumed

  // ---- W-frag half B (kcw 8..15: waves 2,3)
  if (wave >= 2) { WFRAG_WRITE(8) }
  BAR_LGKM;                                  // #6: half B visible

  // ---- GEMM2 pass B: kc2 8..15
  #pragma unroll
  for (int kc2 = 8; kc2 < 16; ++kc2) {
    bf16x8 bfr[4];
    #pragma unroll
    for (int gr = 0; gr < 4; ++gr)
      bfr[gr] = *reinterpret_cast<const bf16x8*>(lds + (size_t)((kc2-8)*4 + gr)*1024 + lane*16);
    bf16x8 afr[4];
    #pragma unroll
    for (int dt = 0; dt < 4; ++dt)
      afr[dt] = *reinterpret_cast<const bf16x8*>(
          vtf + (size_t)(kc2*16 + wave*4 + dt)*512 + lane*8);
    #pragma unroll
    for (int dt = 0; dt < 4; ++dt)
      #pragma unroll
      for (int gr = 0; gr < 4; ++gr)
        oacc[dt][gr] = __builtin_amdgcn_mfma_f32_16x16x32_bf16(afr[dt], bfr[gr], oacc[dt][gr], 0, 0, 0);
  }
  BAR_LGKM;                                  // #7: frag region dead -> private

  // ---- O epilogue (8KB wave-private; 2 passes of 32 rows; CACHED 256B stores
  // -> L2 write-combining absorbs the tail, block retires immediately)
  #pragma unroll
  for (int ho = 0; ho < 2; ++ho) {
    #pragma unroll
    for (int dt = 0; dt < 4; ++dt)
      #pragma unroll
      for (int grl = 0; grl < 2; ++grl) {
        int rowl = grl*16 + c;
        *reinterpret_cast<f32x4*>(priv + rowl*256 + ((dt*64 + g*16) ^ (c << 4))) = oacc[dt][ho*2 + grl];
      }
    asm volatile("s_waitcnt lgkmcnt(0)" ::: "memory");
    #pragma unroll
    for (int p = 0; p < 8; ++p) {
      int rq = lane >> 4, cc = lane & 15;
      int rowp = 4*p + rq;
      f32x4 t = *reinterpret_cast<const f32x4*>(priv + rowp*256 + ((cc*16) ^ ((rowp & 15) << 4)));
      *reinterpret_cast<f32x4*>(
          out_o + (size_t)(browbase + ho*32 + rowp)*DIM + wave*64 + cc*4) = t;
    }
  }
}

extern "C" void kernel_launch(void* const* d_in, const int* in_sizes, int n_in,
                              void* d_out, int out_size, void* d_ws, size_t ws_size,
                              hipStream_t stream) {
  const float* q  = (const float*)d_in[0];
  const float* mk = (const float*)d_in[1];
  const float* mv = (const float*)d_in[2];
  int B = in_sizes[0] / DIM;            // 131072
  float* o = (float*)d_out;
  float* w = o + (size_t)B * DIM;
  float* s = w + (size_t)B * MEMN;
  u16* knf = (u16*)d_ws;                         // 256 KB
  u16* vtf = (u16*)((char*)d_ws + 262144);       // 256 KB
  int nscene = B / 16;                           // 8192 boundary waves
  int nblk_scene = (nscene + 3) / 4;             // 2048 blocks
  aux_kernel<<<256 + nblk_scene, 256, 0, stream>>>(mk, mv, q, knf, vtf, s, B);
  fused_main<<<B / 64, 256, 0, stream>>>(q, knf, vtf, o, w, s);
}

// Round 19
// 141.667 us; speedup vs baseline: 1.7383x; 1.0997x over previous
//
#include <hip/hip_runtime.h>
#include <hip/hip_bf16.h>

#define DIM 256
#define MEMN 512
#define TEMPF 10.0f

typedef float f32x4 __attribute__((ext_vector_type(4)));
typedef __bf16 bf16x8 __attribute__((ext_vector_type(8)));
typedef unsigned int u32;
typedef unsigned short u16;

__device__ __forceinline__ u16 bf16bits(float x) {
  __bf16 h = (__bf16)x;
  return __builtin_bit_cast(u16, h);
}
__device__ __forceinline__ u32 pack2(float a, float b) {
  return (u32)bf16bits(a) | ((u32)bf16bits(b) << 16);
}

// Combined auxiliary kernel (one launch):
//  blocks [0,128):    prep_keys  -> KnFrag (normalized)
//  blocks [128,256):  prep_vals  -> VtFrag
//  blocks [256,...):  scene boundary diffs for i % 16 == 15
__global__ void aux_kernel(const float* __restrict__ keys,
                           const float* __restrict__ mv,
                           const float* __restrict__ q,
                           u16* __restrict__ knf, u16* __restrict__ vtf,
                           float* __restrict__ out_s, int B) {
  int lane = threadIdx.x & 63;
  int wave = threadIdx.x >> 6;
  if (blockIdx.x < 128) {
    int m = blockIdx.x * 4 + wave;
    float4 v = *reinterpret_cast<const float4*>(keys + (size_t)m * DIM + lane * 4);
    float ss = v.x*v.x + v.y*v.y + v.z*v.z + v.w*v.w;
    #pragma unroll
    for (int o = 1; o < 64; o <<= 1) ss += __shfl_xor(ss, o);
    float rn = 1.0f / fmaxf(sqrtf(ss), 1e-12f);
    float vals[4] = {v.x*rn, v.y*rn, v.z*rn, v.w*rn};
    int mt = m >> 4, ml = m & 15;
    #pragma unroll
    for (int t = 0; t < 4; ++t) {
      int d = lane * 4 + t;
      int kc = d >> 5, gg = (d >> 3) & 3, j = d & 7;
      knf[(size_t)((kc*32 + mt)*64 + gg*16 + ml)*8 + j] = bf16bits(vals[t]);
    }
  } else if (blockIdx.x < 256) {
    int m = (blockIdx.x - 128) * 4 + wave;
    float4 v = *reinterpret_cast<const float4*>(mv + (size_t)m * DIM + lane * 4);
    float vals[4] = {v.x, v.y, v.z, v.w};
    int kc = m >> 5, gg = (m >> 3) & 3, j = m & 7;
    #pragma unroll
    for (int t = 0; t < 4; ++t) {
      int d = lane * 4 + t;
      int dt = d >> 4, dl = d & 15;
      vtf[(size_t)((kc*16 + dt)*64 + gg*16 + dl)*8 + j] = bf16bits(vals[t]);
    }
  } else {
    int widx = (blockIdx.x - 256) * 4 + wave;
    int i = widx * 16 + 15;
    if (i > B - 2) return;
    const float* a = q + (size_t)i * DIM + lane * 4;
    float4 x = *reinterpret_cast<const float4*>(a);
    float4 y = *reinterpret_cast<const float4*>(a + DIM);
    float dx = y.x-x.x, dy = y.y-x.y, dz = y.z-x.z, dw = y.w-x.w;
    float sd = dx*dx + dy*dy + dz*dz + dw*dw;
    #pragma unroll
    for (int o = 1; o < 64; o <<= 1) sd += __shfl_xor(sd, o);
    if (lane == 0) out_s[i] = (sqrtf(sd) < 0.8f) ? 1.0f : 0.0f;
  }
}

// lgkm-only barrier: drains this wave's LDS queue, syncs waves, never touches
// vmcnt -> global NT stores drain in the background (round-12/14-validated).
#define BAR_LGKM do { \
    asm volatile("s_waitcnt lgkmcnt(0)" ::: "memory"); \
    __builtin_amdgcn_s_barrier(); \
  } while (0)

// R14 fused_main VERBATIM (both W and O NT stores — the proven 145.1 µs
// configuration). NT Q loads; cached K/V frag reads; mid-kernel W epilogue;
// lgkm-only barriers; full-line NT stores via wave-private LDS transpose.
__global__ __launch_bounds__(256, 2) void fused_main(
    const float* __restrict__ q, const u16* __restrict__ knf,
    const u16* __restrict__ vtf, float* __restrict__ out_o,
    float* __restrict__ out_w, float* __restrict__ out_s) {
  // [0,32768): frag region: Q-frags (gr*8+kc)*1024+lane*16; then wave-private
  //            8KB epilogue quarters; then W-frag halves.
  // [32768,33792): psb row-sum partials; [33792,34048): rnb 1/||q||
  __shared__ __align__(16) char lds[34048];
  const int tid = threadIdx.x;
  const int wave = tid >> 6, lane = tid & 63;
  const int g = lane >> 4, c = lane & 15;
  const int browbase = blockIdx.x * 64;
  const int myrow = browbase + wave * 16 + c;

  float* psb = reinterpret_cast<float*>(lds + 32768);
  float* rnb = reinterpret_cast<float*>(lds + 33792);

  // ---- prologue: own 16 rows' Q (NT loads) -> scene, sum-sq, bf16 frags
  const float* qrow = q + (size_t)myrow * DIM + g * 8;
  float sd = 0.f, ss = 0.f;
  #pragma unroll
  for (int kc = 0; kc < 8; ++kc) {
    f32x4 a = __builtin_nontemporal_load(reinterpret_cast<const f32x4*>(qrow + kc*32));
    f32x4 b = __builtin_nontemporal_load(reinterpret_cast<const f32x4*>(qrow + kc*32 + 4));
    float x[8] = {a[0], a[1], a[2], a[3], b[0], b[1], b[2], b[3]};
    bf16x8 qb;
    #pragma unroll
    for (int e = 0; e < 8; ++e) {
      float nb = __shfl_down(x[e], 1);       // row c+1 (valid c<15)
      float d0 = nb - x[e];
      sd += d0 * d0;
      ss += x[e] * x[e];
      qb[e] = (__bf16)x[e];                  // deferred norm -> exp scale
    }
    *reinterpret_cast<bf16x8*>(lds + (wave*8 + kc)*1024 + lane*16) = qb;
  }
  sd += __shfl_xor(sd, 16); sd += __shfl_xor(sd, 32);
  ss += __shfl_xor(ss, 16); ss += __shfl_xor(ss, 32);
  if (g == 0 && c < 15)
    out_s[myrow] = (sqrtf(sd) < 0.8f) ? 1.0f : 0.0f;
  float rn = 1.0f / fmaxf(sqrtf(ss), 1e-12f);
  if (g == 0) rnb[wave*16 + c] = rn;
  BAR_LGKM;                                  // #1: Q-frags + rn visible

  float scale_r[4];
  #pragma unroll
  for (int gr = 0; gr < 4; ++gr) scale_r[gr] = TEMPF * rnb[gr*16 + c];

  // ---- GEMM1: S^T[m in wave-quarter][64 rows]; A (K) direct from L2
  f32x4 acc[8][4];
  #pragma unroll
  for (int mt = 0; mt < 8; ++mt)
    #pragma unroll
    for (int gr = 0; gr < 4; ++gr) { f32x4 z = {}; acc[mt][gr] = z; }

  #pragma unroll
  for (int kc = 0; kc < 8; ++kc) {
    bf16x8 bfr[4];
    #pragma unroll
    for (int gr = 0; gr < 4; ++gr)
      bfr[gr] = *reinterpret_cast<const bf16x8*>(lds + (gr*8 + kc)*1024 + lane*16);
    bf16x8 afr[8];
    #pragma unroll
    for (int mt = 0; mt < 8; ++mt)
      afr[mt] = *reinterpret_cast<const bf16x8*>(
          knf + (size_t)(kc*32 + wave*8 + mt)*512 + lane*8);
    #pragma unroll
    for (int mt = 0; mt < 8; ++mt)
      #pragma unroll
      for (int gr = 0; gr < 4; ++gr)
        acc[mt][gr] = __builtin_amdgcn_mfma_f32_16x16x32_bf16(afr[mt], bfr[gr], acc[mt][gr], 0, 0, 0);
  }
  // acc[mt][gr][i] = S^T[m=128w+16mt+4g+i][row=gr*16+c]

  // ---- exp + partial row sums
  float psum[4] = {0.f, 0.f, 0.f, 0.f};
  #pragma unroll
  for (int mt = 0; mt < 8; ++mt)
    #pragma unroll
    for (int gr = 0; gr < 4; ++gr)
      #pragma unroll
      for (int i = 0; i < 4; ++i) {
        float e = __expf(acc[mt][gr][i] * scale_r[gr]);
        acc[mt][gr][i] = e;
        psum[gr] += e;
      }
  #pragma unroll
  for (int gr = 0; gr < 4; ++gr) {
    psum[gr] += __shfl_xor(psum[gr], 16);
    psum[gr] += __shfl_xor(psum[gr], 32);
  }
  if (g == 0) {
    #pragma unroll
    for (int gr = 0; gr < 4; ++gr)
      psb[(wave*4 + gr)*16 + c] = psum[gr];
  }
  BAR_LGKM;                                  // #2: partials visible; Q-frags dead

  float rcp_r[4];
  #pragma unroll
  for (int gr = 0; gr < 4; ++gr) {
    float t = psb[(0*4 + gr)*16 + c] + psb[(1*4 + gr)*16 + c]
            + psb[(2*4 + gr)*16 + c] + psb[(3*4 + gr)*16 + c];
    rcp_r[gr] = 1.0f / t;
  }
  // fold rcp: acc becomes final W (f32)
  #pragma unroll
  for (int mt = 0; mt < 8; ++mt)
    #pragma unroll
    for (int gr = 0; gr < 4; ++gr)
      #pragma unroll
      for (int i = 0; i < 4; ++i)
        acc[mt][gr][i] *= rcp_r[gr];

  // ---- W epilogue NOW (wave-private 8KB quarter of frag region):
  // acc[mt][gr][i] = W[row=gr*16+c][m=128w+mt*16+4g+i]; 4 passes of 16 rows;
  // full-line (512B) NT stores -> drain under GEMM2 + O epilogue.
  char* priv = lds + wave * 8192;
  #pragma unroll
  for (int gw = 0; gw < 4; ++gw) {
    #pragma unroll
    for (int mt = 0; mt < 8; ++mt)
      *reinterpret_cast<f32x4*>(priv + c*512 + ((mt*64 + g*16) ^ (c << 4))) = acc[mt][gw];
    asm volatile("s_waitcnt lgkmcnt(0)" ::: "memory");   // wave-private: no barrier
    #pragma unroll
    for (int p = 0; p < 8; ++p) {
      int rq = lane >> 5, cc = lane & 31;
      int rowp = 2*p + rq;
      f32x4 t = *reinterpret_cast<const f32x4*>(priv + rowp*512 + ((cc*16) ^ ((rowp & 15) << 4)));
      __builtin_nontemporal_store(t, reinterpret_cast<f32x4*>(
          out_w + (size_t)(browbase + gw*16 + rowp)*MEMN + wave*128 + cc*4));
    }
  }

  // pack acc -> bf16 pairs; acc dies here (register relief for GEMM2)
  u32 hp[8][8];                              // hp[mt][gr*2+s]
  #pragma unroll
  for (int mt = 0; mt < 8; ++mt)
    #pragma unroll
    for (int gr = 0; gr < 4; ++gr) {
      hp[mt][gr*2+0] = pack2(acc[mt][gr][0], acc[mt][gr][1]);
      hp[mt][gr*2+1] = pack2(acc[mt][gr][2], acc[mt][gr][3]);
    }
  BAR_LGKM;                                  // #3: all epilogue LDS reads done

  // W-frag writer (round-6-verified mapping, from hp):
  // kcw=4w+(mt>>1), lane_t=((mt&1)*2+(g>>1))*16+c, dword j0=(g&1)
#define WFRAG_WRITE(SLOTBASE) \
    _Pragma("unroll") \
    for (int mt = 0; mt < 8; ++mt) { \
      int slot = (4*wave + (mt >> 1) - (SLOTBASE)) * 4; \
      int lane_t = ((mt & 1)*2 + (g >> 1))*16 + c; \
      _Pragma("unroll") \
      for (int gr = 0; gr < 4; ++gr) { \
        u32* dst = reinterpret_cast<u32*>(lds + (size_t)(slot + gr)*1024 + lane_t*16 + (g & 1)*8); \
        dst[0] = hp[mt][gr*2+0]; dst[1] = hp[mt][gr*2+1]; \
      } \
    }

  f32x4 oacc[4][4];
  #pragma unroll
  for (int dt = 0; dt < 4; ++dt)
    #pragma unroll
    for (int gr = 0; gr < 4; ++gr) { f32x4 z = {}; oacc[dt][gr] = z; }

  // ---- W-frag half A (kcw 0..7: waves 0,1)
  if (wave < 2) { WFRAG_WRITE(0) }
  BAR_LGKM;                                  // #4: half A visible

  // ---- GEMM2 pass A: kc2 0..7
  #pragma unroll
  for (int kc2 = 0; kc2 < 8; ++kc2) {
    bf16x8 bfr[4];
    #pragma unroll
    for (int gr = 0; gr < 4; ++gr)
      bfr[gr] = *reinterpret_cast<const bf16x8*>(lds + (size_t)(kc2*4 + gr)*1024 + lane*16);
    bf16x8 afr[4];
    #pragma unroll
    for (int dt = 0; dt < 4; ++dt)
      afr[dt] = *reinterpret_cast<const bf16x8*>(
          vtf + (size_t)(kc2*16 + wave*4 + dt)*512 + lane*8);
    #pragma unroll
    for (int dt = 0; dt < 4; ++dt)
      #pragma unroll
      for (int gr = 0; gr < 4; ++gr)
        oacc[dt][gr] = __builtin_amdgcn_mfma_f32_16x16x32_bf16(afr[dt], bfr[gr], oacc[dt][gr], 0, 0, 0);
  }
  BAR_LGKM;                                  // #5: half A consumed

  // ---- W-frag half B (kcw 8..15: waves 2,3)
  if (wave >= 2) { WFRAG_WRITE(8) }
  BAR_LGKM;                                  // #6: half B visible

  // ---- GEMM2 pass B: kc2 8..15
  #pragma unroll
  for (int kc2 = 8; kc2 < 16; ++kc2) {
    bf16x8 bfr[4];
    #pragma unroll
    for (int gr = 0; gr < 4; ++gr)
      bfr[gr] = *reinterpret_cast<const bf16x8*>(lds + (size_t)((kc2-8)*4 + gr)*1024 + lane*16);
    bf16x8 afr[4];
    #pragma unroll
    for (int dt = 0; dt < 4; ++dt)
      afr[dt] = *reinterpret_cast<const bf16x8*>(
          vtf + (size_t)(kc2*16 + wave*4 + dt)*512 + lane*8);
    #pragma unroll
    for (int dt = 0; dt < 4; ++dt)
      #pragma unroll
      for (int gr = 0; gr < 4; ++gr)
        oacc[dt][gr] = __builtin_amdgcn_mfma_f32_16x16x32_bf16(afr[dt], bfr[gr], oacc[dt][gr], 0, 0, 0);
  }
  BAR_LGKM;                                  // #7: frag region dead -> private

  // ---- O epilogue (8KB wave-private; 2 passes of 32 rows; 256B NT stores)
  #pragma unroll
  for (int ho = 0; ho < 2; ++ho) {
    #pragma unroll
    for (int dt = 0; dt < 4; ++dt)
      #pragma unroll
      for (int grl = 0; grl < 2; ++grl) {
        int rowl = grl*16 + c;
        *reinterpret_cast<f32x4*>(priv + rowl*256 + ((dt*64 + g*16) ^ (c << 4))) = oacc[dt][ho*2 + grl];
      }
    asm volatile("s_waitcnt lgkmcnt(0)" ::: "memory");
    #pragma unroll
    for (int p = 0; p < 8; ++p) {
      int rq = lane >> 4, cc = lane & 15;
      int rowp = 4*p + rq;
      f32x4 t = *reinterpret_cast<const f32x4*>(priv + rowp*256 + ((cc*16) ^ ((rowp & 15) << 4)));
      __builtin_nontemporal_store(t, reinterpret_cast<f32x4*>(
          out_o + (size_t)(browbase + ho*32 + rowp)*DIM + wave*64 + cc*4));
    }
  }
}

extern "C" void kernel_launch(void* const* d_in, const int* in_sizes, int n_in,
                              void* d_out, int out_size, void* d_ws, size_t ws_size,
                              hipStream_t stream) {
  const float* q  = (const float*)d_in[0];
  const float* mk = (const float*)d_in[1];
  const float* mv = (const float*)d_in[2];
  int B = in_sizes[0] / DIM;            // 131072
  float* o = (float*)d_out;
  float* w = o + (size_t)B * DIM;
  float* s = w + (size_t)B * MEMN;
  u16* knf = (u16*)d_ws;                         // 256 KB
  u16* vtf = (u16*)((char*)d_ws + 262144);       // 256 KB
  int nscene = B / 16;                           // 8192 boundary waves
  int nblk_scene = (nscene + 3) / 4;             // 2048 blocks
  aux_kernel<<<256 + nblk_scene, 256, 0, stream>>>(mk, mv, q, knf, vtf, s, B);
  fused_main<<<B / 64, 256, 0, stream>>>(q, knf, vtf, o, w, s);
}